// Round 2
// 426.814 us; speedup vs baseline: 1.0321x; 1.0321x over previous
//
#include <hip/hip_runtime.h>
#include <stdint.h>

// Self-attention, B=8, S=2048, D=1024, fp32 in/out, bf16 MFMA compute.
//
// Pipeline:
//   1. k_cvt: x -> xb (bf16), zero l;  k_cvt3: Wq/Wk/Wv -> Wb
//   2. k_qkv3 (z=0,1): Q/K = xb @ W^T + b   (z=2): Vt = (xb @ Wv^T + bv)^T
//   3. k_scores: U = exp((Q @ K^T)/32) bf16 + atomic per-row sums into l
//      (scores bounded |s|<=|q||k|/32 -> no max-subtraction needed)
//   4. k_pv   : out = (U @ Vt^T) * (1/l[row])  (fp32 out)
//
// R6 changes (resubmitted R7 — R6 bench was an infra failure, never ran):
//  - __shared__ hoisted out of gemm_bt_core into the kernels and passed as a
//    pointer. k_qkv3 instantiates the core twice (EPI 0 and EPI 3); the
//    function-local __shared__ was replicated per instantiation ->
//    LDS_Block_Size 69632 (2x34816) -> 2 blocks/CU, Occupancy 21%. One
//    shared allocation restores 4 blocks/CU (4x34816=139264 <= 160K).
//    Grid quantization stays exact: qkv3 3072 blocks = 3 full waves at
//    4/CU x 256 CU, scores 2048 = 2, pv 1024 = 1.
//  - (kept from R5) batch<->XCD pinning for k_scores/k_pv (b = lid&7 == xcd,
//    per-XCD working set = one batch's K/Vt = 4 MB = L2), merged z=3 qkv
//    launch, l zeroed inside k_cvt, XOR k-chunk LDS swizzle (conflicts = 0).
//
// ws layout:
//   [0,       33.5M)  Q        16384x1024 bf16
//   [33.5M,   67.1M)  K        16384x1024 bf16
//   [67.1M,  100.7M)  Vt       8 x 1024x2048 bf16
//   [100.7M, 167.8M)  U        8 x 2048x2048 bf16  (first half aliases xb,
//                                                   dead before U written)
//   [167.8M, 174.1M)  Wb       3 x 1024x1024 bf16
//   [174.1M, ...)     l        16384 fp32 (attn row sums, atomic)

typedef __bf16 bf16_t;
typedef __bf16 bf16x8 __attribute__((ext_vector_type(8)));
typedef __bf16 bf16x4 __attribute__((ext_vector_type(4)));
typedef float f32x4 __attribute__((ext_vector_type(4)));

__device__ __forceinline__ void gload_lds16(const bf16_t* g, bf16_t* l) {
    __builtin_amdgcn_global_load_lds((const __attribute__((address_space(1))) void*)g,
                                     (__attribute__((address_space(3))) void*)l,
                                     16, 0, 0);
}

// ---------------------------------------------------------------------------
// Core GEMM: C[M,N] = A[M,K] @ B[N,K]^T, bf16 row-major K-contiguous.
// Tile 128x128, BK=64, 256 threads (4 waves 2x2), 4x4 16x16x32 MFMAs/wave.
// A and B staged via global_load_lds with XOR k-chunk swizzle (conflict-free,
// measured SQ_LDS_BANK_CONFLICT = 0).
// smem: caller-provided 128*136 bf16 (34816 B); loop uses 32 KB (As/Bs),
// EPI 0/1 epilogue reuses it as a 128x136 repack buffer.
// EPI: 0 = (+bias[col]) -> bf16, LDS-repacked vector stores
//      1 = exp(acc*scale) -> bf16, LDS-repacked vector stores + atomic row
//          sums into aux
//      2 = acc*(1/aux[row]) -> fp32 direct stores
//      3 = (+bias[col]) -> bf16 TRANSPOSED into Vt[b][col][row]
// ---------------------------------------------------------------------------
template <int EPI, int LDA, int LDB>
__device__ __forceinline__ void gemm_bt_core(
    bf16_t* __restrict__ smem,
    const bf16_t* __restrict__ A,
    const bf16_t* __restrict__ B,
    bf16_t* __restrict__ Cb, float* __restrict__ Cf, int ldc,
    float* __restrict__ aux, float scale, int K,
    int m0, int n0)
{
    bf16_t* As = smem;
    bf16_t* Bs = smem + 8192;

    const int t    = threadIdx.x;
    const int lane = t & 63;
    const int wave = t >> 6;
    const int wm   = wave >> 1;
    const int wn   = wave & 1;
    const int lr   = lane & 15;
    const int quad = lane >> 4;
    const int swz  = lr & 7;             // read-side xor key (= row&7)

    const int srow   = t >> 3;                        // 0..31
    const int schunk = ((t & 7) ^ (srow & 7)) * 8;    // swizzled global chunk

    f32x4 acc[4][4];
#pragma unroll
    for (int i = 0; i < 4; i++)
#pragma unroll
        for (int j = 0; j < 4; j++) acc[i][j] = (f32x4){0.f, 0.f, 0.f, 0.f};

    const bf16_t* Ag = A + (size_t)(m0 + srow) * LDA + schunk;
    const bf16_t* Bg = B + (size_t)(n0 + srow) * LDB + schunk;

    for (int kt = 0; kt < K; kt += 64) {
#pragma unroll
        for (int j = 0; j < 4; j++) {
            gload_lds16(Ag + (size_t)j * 32 * LDA + kt, As + j * 2048 + t * 8);
            gload_lds16(Bg + (size_t)j * 32 * LDB + kt, Bs + j * 2048 + t * 8);
        }
        __syncthreads();

#pragma unroll
        for (int s = 0; s < 2; s++) {
            const int koff = ((s * 4 + quad) ^ swz) * 8;   // swizzled slot
            bf16x8 af[4], bfr[4];
#pragma unroll
            for (int i = 0; i < 4; i++)
                af[i] = *(const bf16x8*)(As + (wm * 64 + i * 16 + lr) * 64 + koff);
#pragma unroll
            for (int j = 0; j < 4; j++)
                bfr[j] = *(const bf16x8*)(Bs + (wn * 64 + j * 16 + lr) * 64 + koff);
#pragma unroll
            for (int i = 0; i < 4; i++)
#pragma unroll
                for (int j = 0; j < 4; j++)
                    acc[i][j] = __builtin_amdgcn_mfma_f32_16x16x32_bf16(af[i], bfr[j], acc[i][j], 0, 0, 0);
        }
        __syncthreads();
    }

    // Epilogue. C/D layout: col = lane&15, row = quad*4 + reg.
    if (EPI == 0 || EPI == 1) {
        // stage to LDS (row stride 136), then 16-B coalesced stores
#pragma unroll
        for (int j = 0; j < 4; j++) {
            const int col = wn * 64 + j * 16 + lr;
            const float bv = (EPI == 0) ? aux[n0 + col] : 0.f;
#pragma unroll
            for (int i = 0; i < 4; i++) {
                const int row = wm * 64 + i * 16 + quad * 4;
#pragma unroll
                for (int r = 0; r < 4; r++) {
                    float v = (EPI == 0) ? (acc[i][j][r] + bv)
                                         : __expf(acc[i][j][r] * scale);
                    smem[(row + r) * 136 + col] = (__bf16)v;
                }
            }
        }
        __syncthreads();
        const int lr2  = t >> 1;       // row 0..127
        const int half = t & 1;        // col half
        float part = 0.f;
#pragma unroll
        for (int c8 = 0; c8 < 8; c8++) {
            const int col0 = half * 64 + c8 * 8;
            bf16x8 v = *(const bf16x8*)(smem + lr2 * 136 + col0);
            *(bf16x8*)(Cb + (size_t)(m0 + lr2) * ldc + n0 + col0) = v;
            if (EPI == 1) {
#pragma unroll
                for (int e = 0; e < 8; e++) part += (float)v[e];
            }
        }
        if (EPI == 1) {
            part += __shfl_xor(part, 1);
            if (half == 0) atomicAdd(aux + m0 + lr2, part);
        }
    } else if (EPI == 2) {
#pragma unroll
        for (int i = 0; i < 4; i++) {
            const int row = m0 + wm * 64 + i * 16 + quad * 4;
#pragma unroll
            for (int r = 0; r < 4; r++) {
                const float s = 1.0f / aux[row + r];
                float* crow = Cf + (size_t)(row + r) * ldc + n0 + wn * 64 + lr;
#pragma unroll
                for (int j = 0; j < 4; j++)
                    crow[j * 16] = acc[i][j][r] * s;
            }
        }
    } else {
        // EPI 3: transposed write into Vt[b][col][row], rows global = b*2048+s
#pragma unroll
        for (int j = 0; j < 4; j++) {
            const int col = n0 + wn * 64 + j * 16 + lr;      // d index
            const float bv = aux[col];
#pragma unroll
            for (int i = 0; i < 4; i++) {
                const int rowg = m0 + wm * 64 + i * 16 + quad * 4;  // global s
                const int b    = rowg >> 11;
                const int s    = rowg & 2047;
                bf16x4 p = { (__bf16)(acc[i][j][0] + bv), (__bf16)(acc[i][j][1] + bv),
                             (__bf16)(acc[i][j][2] + bv), (__bf16)(acc[i][j][3] + bv) };
                *(bf16x4*)(Cb + ((size_t)b << 21) + ((size_t)col << 11) + s) = p;
            }
        }
    }
}

// --------------------------- kernel wrappers -------------------------------

// Q/K/Vt projection, grid (8,128,3). xcd = lid&7; within an XCD, x' (weight
// n-tile) fast, y' (A-strip) middle, z' (which matrix) slowest -> W_z (2 MB)
// L2-pinned per phase, xb strips read via L2/L3.
__global__ __launch_bounds__(256) void k_qkv3(
    const bf16_t* __restrict__ xb, const bf16_t* __restrict__ Wb,
    bf16_t* __restrict__ Q, bf16_t* __restrict__ Vt,
    const float* __restrict__ bq, const float* __restrict__ bk,
    const float* __restrict__ bv)
{
    __shared__ bf16_t smem[128 * 136];
    const int lid  = blockIdx.x + 8 * blockIdx.y + 1024 * blockIdx.z;
    const int xcd  = lid & 7;
    const int slot = lid >> 3;          // 0..383
    const int z    = slot >> 7;         // 0..2, slowest
    const int rem  = slot & 127;
    const int xt   = rem & 7;           // fast
    const int yt   = xcd * 16 + (rem >> 3);
    if (z < 2) {
        float* bias = (float*)((z == 0) ? bq : bk);
        gemm_bt_core<0, 1024, 1024>(smem, xb, Wb + (size_t)z * 1048576,
                                    Q + (size_t)z * 16777216, nullptr, 1024,
                                    bias, 0.f, 1024, yt * 128, xt * 128);
    } else {
        gemm_bt_core<3, 1024, 1024>(smem, xb, Wb + (size_t)2 * 1048576,
                                    Vt, nullptr, 0,
                                    (float*)bv, 0.f, 1024, yt * 128, xt * 128);
    }
}

// scores, grid (16,16,8): batch = lid&7 == XCD -> per-XCD working set is one
// batch's K matrix (4 MB = L2). Within XCD: x-tile fast (K sweep), Q-strip
// pinned per y-tile.
__global__ __launch_bounds__(256) void k_scores(
    const bf16_t* __restrict__ Q, const bf16_t* __restrict__ Km,
    bf16_t* __restrict__ U, float* __restrict__ l)
{
    __shared__ bf16_t smem[128 * 136];
    const int lid = blockIdx.x + 16 * blockIdx.y + 256 * blockIdx.z;
    const int b   = lid & 7;
    const int si  = lid >> 3;           // 0..255
    const int xt  = si & 15;
    const int yt  = si >> 4;
    gemm_bt_core<1, 1024, 1024>(smem, Q + (size_t)b * 2048 * 1024,
                                Km + (size_t)b * 2048 * 1024,
                                U + (size_t)b * 2048 * 2048, nullptr, 2048,
                                l + b * 2048, 0.03125f, 1024,
                                yt * 128, xt * 128);
}

// PV, grid (8,16,8): batch = lid&7 == XCD -> per-XCD working set is one
// batch's Vt (4 MB = L2). x-tile (Vt d-slab) fast, U-strip pinned per y-tile.
__global__ __launch_bounds__(256) void k_pv(
    const bf16_t* __restrict__ U, const bf16_t* __restrict__ Vt,
    float* __restrict__ Out, float* __restrict__ l)
{
    __shared__ bf16_t smem[128 * 136];
    const int lid = blockIdx.x + 8 * blockIdx.y + 128 * blockIdx.z;
    const int b   = lid & 7;
    const int si  = lid >> 3;           // 0..127
    const int xt  = si & 7;
    const int yt  = si >> 3;
    gemm_bt_core<2, 2048, 2048>(smem, U + (size_t)b * 2048 * 2048,
                                Vt + (size_t)b * 1024 * 2048,
                                nullptr, Out + (size_t)b * 2048 * 1024, 1024,
                                l + b * 2048, 0.f, 2048,
                                yt * 128, xt * 128);
}

// fp32 -> bf16 conversion, 4 elems/thread; also zeroes l (16384 floats)
__global__ __launch_bounds__(256) void k_cvt(
    const float* __restrict__ in, bf16_t* __restrict__ out, long ngroups,
    float* __restrict__ l)
{
    long idx    = (long)blockIdx.x * blockDim.x + threadIdx.x;
    long stride = (long)gridDim.x * blockDim.x;
    if (blockIdx.x < 64) l[blockIdx.x * 256 + threadIdx.x] = 0.f;
    for (long i = idx; i < ngroups; i += stride) {
        float4 v = ((const float4*)in)[i];
        bf16x4 o = { (__bf16)v.x, (__bf16)v.y, (__bf16)v.z, (__bf16)v.w };
        ((bf16x4*)out)[i] = o;
    }
}

// fused 3-weight fp32 -> bf16 (z selects source)
__global__ __launch_bounds__(256) void k_cvt3(
    const float* __restrict__ w0, const float* __restrict__ w1,
    const float* __restrict__ w2, bf16_t* __restrict__ out)
{
    const int z = blockIdx.z;
    const float* in = (z == 0) ? w0 : (z == 1) ? w1 : w2;
    bf16_t* o = out + (size_t)z * 1048576;
    long i = (long)blockIdx.x * blockDim.x + threadIdx.x;
    float4 v = ((const float4*)in)[i];
    bf16x4 ov = { (__bf16)v.x, (__bf16)v.y, (__bf16)v.z, (__bf16)v.w };
    ((bf16x4*)o)[i] = ov;
}

// ---------------------------------------------------------------------------

extern "C" void kernel_launch(void* const* d_in, const int* in_sizes, int n_in,
                              void* d_out, int out_size, void* d_ws, size_t ws_size,
                              hipStream_t stream)
{
    const float* x  = (const float*)d_in[0];
    const float* Wq = (const float*)d_in[1];
    const float* bq = (const float*)d_in[2];
    const float* Wk = (const float*)d_in[3];
    const float* bk = (const float*)d_in[4];
    const float* Wv = (const float*)d_in[5];
    const float* bv = (const float*)d_in[6];

    bf16_t* Q    = (bf16_t*)d_ws;              // 16384x1024
    bf16_t* Km   = Q + 16777216;               // 16384x1024
    bf16_t* Vt   = Km + 16777216;              // 8 x 1024x2048
    bf16_t* U    = Vt + 16777216;              // 8 x 2048x2048
    bf16_t* xb   = U;                          // alias: dead before U written
    bf16_t* Wb   = U + 33554432;               // 3 x 1024x1024
    float*  l    = (float*)(Wb + 3145728);     // 16384

    k_cvt<<<dim3(2048), 256, 0, stream>>>(x, xb, 16777216 / 4, l);
    k_cvt3<<<dim3(1024, 1, 3), 256, 0, stream>>>(Wq, Wk, Wv, Wb);
    k_qkv3<<<dim3(8, 128, 3), 256, 0, stream>>>(xb, Wb, Q, Vt, bq, bk, bv);
    k_scores<<<dim3(16, 16, 8), 256, 0, stream>>>(Q, Km, U, l);
    k_pv<<<dim3(8, 16, 8), 256, 0, stream>>>(U, Vt, (float*)d_out, l);
}

// Round 3
// 383.677 us; speedup vs baseline: 1.1482x; 1.1124x over previous
//
#include <hip/hip_runtime.h>
#include <stdint.h>

// Self-attention, B=8, S=2048, D=1024, fp32 in/out, bf16 MFMA compute.
//
// Pipeline:
//   1. k_cvt: x -> xb (bf16), zero l;  k_cvt3: Wq/Wk/Wv -> Wb
//   2. k_qkv3 (z=0,1): Q/K = xb @ W^T + b   (z=2): Vt = (xb @ Wv^T + bv)^T
//   3. k_scores: U = exp((Q @ K^T)/32) bf16 + atomic per-row sums into l
//   4. k_pv   : out = (U @ Vt^T) * (1/l[row])  (fp32 out)
//
// R8: 256x256-tile, 8-wave, BK=32, ring-4 LDS pipelined GEMM core
// (plain-HIP port of the HK/m201 8-phase family):
//  - 128 KiB LDS: 4 ring buffers x (A 256x32 + B 256x32). global_load_lds
//    staging with inverse-swizzled global source (chunk q^(row&3)); ds_read
//    applies same XOR -> 2-way bank aliasing only (free).
//  - Per K32-step, 2 phases: {ds_read frags; s_barrier+sched_barrier(0);
//    setprio(1) 16 MFMA setprio(0)}. Stage tile t+3 in phase 2; counted
//    s_waitcnt vmcnt(8) BEFORE the phase-2 barrier (never drains to 0 in
//    steady state; tail 8->4->0). Race-free: vmcnt-before-barrier makes
//    tile-t landing cross-wave-visible; stages issue after B_{t,1}, by which
//    all waves' tile-(t-1) reads are lgkm-retired (ring distance 3 = dead).
//  - Rationale: m97-style 128^2/2-barrier structure measured at its known
//    ~structure ceiling (716 TF at K=1024, 30% MfmaUtil); R6's LDS fix was
//    neutral (occupancy was VGPR-bound). Only the deep-pipelined 256^2
//    schedule breaks it (1563-1728 TF in learn_hip m201).
//  - Kept: batch<->XCD pinning (b = lid&7), z-slowest W-pinning for qkv3,
//    l zeroed in k_cvt, exp-sum softmax (no max subtraction; |s|<=|q||k|/32).
//
// ws layout:
//   [0,       33.5M)  Q        16384x1024 bf16
//   [33.5M,   67.1M)  K        16384x1024 bf16
//   [67.1M,  100.7M)  Vt       8 x 1024x2048 bf16
//   [100.7M, 167.8M)  U        8 x 2048x2048 bf16  (first half aliases xb)
//   [167.8M, 174.1M)  Wb       3 x 1024x1024 bf16
//   [174.1M, ...)     l        16384 fp32 (attn row sums, atomic)

typedef __bf16 bf16_t;
typedef __bf16 bf16x8 __attribute__((ext_vector_type(8)));
typedef __bf16 bf16x4 __attribute__((ext_vector_type(4)));
typedef float f32x4 __attribute__((ext_vector_type(4)));

__device__ __forceinline__ void gload_lds16(const bf16_t* g, bf16_t* l) {
    __builtin_amdgcn_global_load_lds((const __attribute__((address_space(1))) void*)g,
                                     (__attribute__((address_space(3))) void*)l,
                                     16, 0, 0);
}

// ---------------------------------------------------------------------------
// Core GEMM: C[M,N] = A[M,K] @ B[N,K]^T, bf16 row-major K-contiguous.
// Tile 256x256, BK=32, 512 threads (8 waves 2Mx4N), per-wave 8x4 16x16x32
// MFMA fragments (output 128x64 per wave).
// lds: caller-provided 65536 bf16 (128 KiB): 4 ring buffers of 16384 elems
// (A tile 8192 + B tile 8192). Epilogue (EPI 0/1) reuses it as 128x264 repack.
// EPI: 0 = (+bias[col]) -> bf16 coalesced stores
//      1 = exp(acc*scale) -> bf16 stores + atomic row sums into aux
//      2 = acc*(1/aux[row]) -> fp32 direct stores
//      3 = (+bias[col]) -> bf16 TRANSPOSED into Vt[b][col][row]
// ---------------------------------------------------------------------------
template <int EPI, int LDA, int LDB>
__device__ __forceinline__ void gemm256_core(
    bf16_t* __restrict__ lds,
    const bf16_t* __restrict__ A,
    const bf16_t* __restrict__ B,
    bf16_t* __restrict__ Cb, float* __restrict__ Cf, int ldc,
    float* __restrict__ aux, float scale, int K,
    int m0, int n0)
{
    const int t    = threadIdx.x;         // 0..511
    const int lane = t & 63;
    const int wave = t >> 6;              // 0..7
    const int wm   = wave >> 2;           // 0..1  (M half)
    const int wn   = wave & 3;            // 0..3  (N quarter)
    const int lr   = lane & 15;
    const int quad = lane >> 4;

    // Staging: thread t owns 16B slots {t, 512+t} of each tile half.
    // Slot p holds global (row = p>>2, chunk q = (p&3)^(row&3)) -- the
    // inverse of the read-side XOR, so reads see a linear (row, chunk) map.
    const int rowS = t >> 2;                       // 0..127
    const int qS   = (t & 3) ^ (rowS & 3);
    const bf16_t* Ag = A + (size_t)(m0 + rowS) * LDA + qS * 8;
    const bf16_t* Bg = B + (size_t)(n0 + rowS) * LDB + qS * 8;
    const int dst0 = t * 8;                        // elems

    // Fragment read offsets (elems): row-major 256x32, chunk XOR-swizzled.
    const int ko   = (quad ^ (lr & 3)) * 8;
    const int aoff = (wm * 128 + lr) * 32 + ko;
    const int boff = (wn * 64 + lr) * 32 + ko;

    f32x4 acc[8][4];
#pragma unroll
    for (int i = 0; i < 8; i++)
#pragma unroll
        for (int j = 0; j < 4; j++) acc[i][j] = (f32x4){0.f, 0.f, 0.f, 0.f};

    const int T = K >> 5;   // K32-steps (>= 3)

    // Prologue: stage tiles 0,1,2 (12 loads/thread), then require tile 0.
#pragma unroll
    for (int tt = 0; tt < 3; ++tt) {
        bf16_t* Ab = lds + tt * 16384;
        bf16_t* Bb = Ab + 8192;
        const int kt = tt * 32;
        gload_lds16(Ag + kt,                     Ab + dst0);
        gload_lds16(Ag + kt + (size_t)128 * LDA, Ab + 4096 + dst0);
        gload_lds16(Bg + kt,                     Bb + dst0);
        gload_lds16(Bg + kt + (size_t)128 * LDB, Bb + 4096 + dst0);
    }
    asm volatile("s_waitcnt vmcnt(8)" ::: "memory");
    __builtin_amdgcn_s_barrier();
    __builtin_amdgcn_sched_barrier(0);

    for (int tk = 0; tk < T; ++tk) {
        const bf16_t* Ab = lds + (tk & 3) * 16384;
        const bf16_t* Bb = Ab + 8192;
        bf16x8 af[8], bfr[4];
        // ---- phase 1: read A lo-half frags + all B frags, compute i=0..3
#pragma unroll
        for (int i = 0; i < 4; ++i)
            af[i] = *(const bf16x8*)(Ab + aoff + 512 * i);
#pragma unroll
        for (int j = 0; j < 4; ++j)
            bfr[j] = *(const bf16x8*)(Bb + boff + 512 * j);
        __builtin_amdgcn_s_barrier();              // B_{t,1}
        __builtin_amdgcn_sched_barrier(0);
        __builtin_amdgcn_s_setprio(1);
#pragma unroll
        for (int i = 0; i < 4; ++i)
#pragma unroll
            for (int j = 0; j < 4; ++j)
                acc[i][j] = __builtin_amdgcn_mfma_f32_16x16x32_bf16(af[i], bfr[j], acc[i][j], 0, 0, 0);
        __builtin_amdgcn_s_setprio(0);
        // ---- phase 2: read A hi-half frags, stage tile t+3, compute i=4..7
#pragma unroll
        for (int i = 4; i < 8; ++i)
            af[i] = *(const bf16x8*)(Ab + aoff + 512 * i);
        if (tk + 3 < T) {
            bf16_t* An = lds + ((tk + 3) & 3) * 16384;   // = buf of tile t-1 (dead)
            bf16_t* Bn = An + 8192;
            const int kt = (tk + 3) * 32;
            gload_lds16(Ag + kt,                     An + dst0);
            gload_lds16(Ag + kt + (size_t)128 * LDA, An + 4096 + dst0);
            gload_lds16(Bg + kt,                     Bn + dst0);
            gload_lds16(Bg + kt + (size_t)128 * LDB, Bn + 4096 + dst0);
            asm volatile("s_waitcnt vmcnt(8)" ::: "memory");   // tiles t+2,t+3 in flight
        } else if (tk + 2 < T) {
            asm volatile("s_waitcnt vmcnt(4)" ::: "memory");
        } else {
            asm volatile("s_waitcnt vmcnt(0)" ::: "memory");
        }
        __builtin_amdgcn_s_barrier();              // B_{t,2}: tile t+1 now visible to all
        __builtin_amdgcn_sched_barrier(0);
        __builtin_amdgcn_s_setprio(1);
#pragma unroll
        for (int i = 4; i < 8; ++i)
#pragma unroll
            for (int j = 0; j < 4; ++j)
                acc[i][j] = __builtin_amdgcn_mfma_f32_16x16x32_bf16(af[i], bfr[j], acc[i][j], 0, 0, 0);
        __builtin_amdgcn_s_setprio(0);
    }

    // Epilogue. C/D frag layout: col = lane&15, row = quad*4 + reg.
    if (EPI == 0 || EPI == 1) {
        // Repack half-by-half (wm half h -> 128x256) in LDS (stride 264),
        // then coalesced 16B stores; EPI1 also accumulates row sums.
#pragma unroll
        for (int h = 0; h < 2; ++h) {
            __syncthreads();
            if (wm == h) {
#pragma unroll
                for (int j = 0; j < 4; ++j) {
                    const int col = wn * 64 + j * 16 + lr;
                    const float bv = (EPI == 0) ? aux[n0 + col] : 0.f;
#pragma unroll
                    for (int i = 0; i < 8; ++i) {
                        const int row = i * 16 + quad * 4;
#pragma unroll
                        for (int r = 0; r < 4; ++r) {
                            float v = (EPI == 0) ? (acc[i][j][r] + bv)
                                                 : __expf(acc[i][j][r] * scale);
                            lds[(row + r) * 264 + col] = (__bf16)v;
                        }
                    }
                }
            }
            __syncthreads();
            const int r2 = t >> 2;            // 0..127
            const int c0 = (t & 3) * 8;       // interleaved col chunks
            float part = 0.f;
#pragma unroll
            for (int c = 0; c < 8; ++c) {
                bf16x8 v = *(const bf16x8*)(lds + r2 * 264 + c0 + c * 32);
                *(bf16x8*)(Cb + (size_t)(m0 + h * 128 + r2) * ldc + n0 + c0 + c * 32) = v;
                if (EPI == 1) {
#pragma unroll
                    for (int e = 0; e < 8; ++e) part += (float)v[e];
                }
            }
            if (EPI == 1) {
                part += __shfl_xor(part, 1);
                part += __shfl_xor(part, 2);
                if ((t & 3) == 0) atomicAdd(aux + m0 + h * 128 + r2, part);
            }
        }
    } else if (EPI == 2) {
#pragma unroll
        for (int i = 0; i < 8; ++i) {
            const int rowb = m0 + wm * 128 + i * 16 + quad * 4;
#pragma unroll
            for (int r = 0; r < 4; ++r) {
                const float s = 1.0f / aux[rowb + r];
                float* crow = Cf + (size_t)(rowb + r) * ldc + n0 + wn * 64 + lr;
#pragma unroll
                for (int j = 0; j < 4; ++j)
                    crow[j * 16] = acc[i][j][r] * s;
            }
        }
    } else {
        // EPI 3: transposed write into Vt[b][col][row], rows global = b*2048+s
#pragma unroll
        for (int j = 0; j < 4; ++j) {
            const int col = n0 + wn * 64 + j * 16 + lr;      // d index
            const float bv = aux[col];
#pragma unroll
            for (int i = 0; i < 8; ++i) {
                const int rowg = m0 + wm * 128 + i * 16 + quad * 4;  // global s
                const int b    = rowg >> 11;
                const int s    = rowg & 2047;
                bf16x4 p = { (__bf16)(acc[i][j][0] + bv), (__bf16)(acc[i][j][1] + bv),
                             (__bf16)(acc[i][j][2] + bv), (__bf16)(acc[i][j][3] + bv) };
                *(bf16x4*)(Cb + ((size_t)b << 21) + ((size_t)col << 11) + s) = p;
            }
        }
    }
}

// --------------------------- kernel wrappers -------------------------------

// Q/K/Vt projection, grid (8,96) = 768 blocks. xcd = lid&7; within an XCD,
// x' (weight n-tile, 4) fast, y' (A-strip, 8) middle, z' (matrix) slowest
// -> W_z (2 MB) L2-pinned per phase.
__global__ __launch_bounds__(512, 1) void k_qkv3(
    const bf16_t* __restrict__ xb, const bf16_t* __restrict__ Wb,
    bf16_t* __restrict__ Q, bf16_t* __restrict__ Vt,
    const float* __restrict__ bq, const float* __restrict__ bk,
    const float* __restrict__ bv)
{
    __shared__ bf16_t lds[65536];
    const int lid  = blockIdx.x + 8 * blockIdx.y;
    const int xcd  = lid & 7;
    const int slot = lid >> 3;          // 0..95
    const int z    = slot >> 5;         // 0..2, slowest
    const int rem  = slot & 31;
    const int xt   = rem & 3;           // fast (4 n-tiles)
    const int yt   = xcd * 8 + (rem >> 2);
    if (z < 2) {
        float* bias = (float*)((z == 0) ? bq : bk);
        gemm256_core<0, 1024, 1024>(lds, xb, Wb + (size_t)z * 1048576,
                                    Q + (size_t)z * 16777216, nullptr, 1024,
                                    bias, 0.f, 1024, yt * 256, xt * 256);
    } else {
        gemm256_core<3, 1024, 1024>(lds, xb, Wb + (size_t)2 * 1048576,
                                    Vt, nullptr, 0,
                                    (float*)bv, 0.f, 1024, yt * 256, xt * 256);
    }
}

// scores, grid (8,64) = 512 blocks: batch = lid&7 == XCD -> per-XCD working
// set is one batch's K matrix (4 MB = L2). x-tile fast.
__global__ __launch_bounds__(512, 1) void k_scores(
    const bf16_t* __restrict__ Q, const bf16_t* __restrict__ Km,
    bf16_t* __restrict__ U, float* __restrict__ l)
{
    __shared__ bf16_t lds[65536];
    const int lid = blockIdx.x + 8 * blockIdx.y;
    const int b   = lid & 7;
    const int si  = lid >> 3;           // 0..63
    const int xt  = si & 7;
    const int yt  = si >> 3;
    gemm256_core<1, 1024, 1024>(lds, Q + (size_t)b * 2048 * 1024,
                                Km + (size_t)b * 2048 * 1024,
                                U + (size_t)b * 2048 * 2048, nullptr, 2048,
                                l + b * 2048, 0.03125f, 1024,
                                yt * 256, xt * 256);
}

// PV, grid (8,32) = 256 blocks: batch = lid&7 == XCD -> per-XCD working set
// is one batch's Vt (4 MB = L2).
__global__ __launch_bounds__(512, 1) void k_pv(
    const bf16_t* __restrict__ U, const bf16_t* __restrict__ Vt,
    float* __restrict__ Out, float* __restrict__ l)
{
    __shared__ bf16_t lds[65536];
    const int lid = blockIdx.x + 8 * blockIdx.y;
    const int b   = lid & 7;
    const int si  = lid >> 3;           // 0..31
    const int xt  = si & 3;
    const int yt  = si >> 2;
    gemm256_core<2, 2048, 2048>(lds, U + (size_t)b * 2048 * 2048,
                                Vt + (size_t)b * 1024 * 2048,
                                nullptr, Out + (size_t)b * 2048 * 1024, 1024,
                                l + b * 2048, 0.f, 2048,
                                yt * 256, xt * 256);
}

// fp32 -> bf16 conversion, 4 elems/thread; also zeroes l (16384 floats)
__global__ __launch_bounds__(256) void k_cvt(
    const float* __restrict__ in, bf16_t* __restrict__ out, long ngroups,
    float* __restrict__ l)
{
    long idx    = (long)blockIdx.x * blockDim.x + threadIdx.x;
    long stride = (long)gridDim.x * blockDim.x;
    if (blockIdx.x < 64) l[blockIdx.x * 256 + threadIdx.x] = 0.f;
    for (long i = idx; i < ngroups; i += stride) {
        float4 v = ((const float4*)in)[i];
        bf16x4 o = { (__bf16)v.x, (__bf16)v.y, (__bf16)v.z, (__bf16)v.w };
        ((bf16x4*)out)[i] = o;
    }
}

// fused 3-weight fp32 -> bf16 (z selects source)
__global__ __launch_bounds__(256) void k_cvt3(
    const float* __restrict__ w0, const float* __restrict__ w1,
    const float* __restrict__ w2, bf16_t* __restrict__ out)
{
    const int z = blockIdx.z;
    const float* in = (z == 0) ? w0 : (z == 1) ? w1 : w2;
    bf16_t* o = out + (size_t)z * 1048576;
    long i = (long)blockIdx.x * blockDim.x + threadIdx.x;
    float4 v = ((const float4*)in)[i];
    bf16x4 ov = { (__bf16)v.x, (__bf16)v.y, (__bf16)v.z, (__bf16)v.w };
    ((bf16x4*)o)[i] = ov;
}

// ---------------------------------------------------------------------------

extern "C" void kernel_launch(void* const* d_in, const int* in_sizes, int n_in,
                              void* d_out, int out_size, void* d_ws, size_t ws_size,
                              hipStream_t stream)
{
    const float* x  = (const float*)d_in[0];
    const float* Wq = (const float*)d_in[1];
    const float* bq = (const float*)d_in[2];
    const float* Wk = (const float*)d_in[3];
    const float* bk = (const float*)d_in[4];
    const float* Wv = (const float*)d_in[5];
    const float* bv = (const float*)d_in[6];

    bf16_t* Q    = (bf16_t*)d_ws;              // 16384x1024
    bf16_t* Km   = Q + 16777216;               // 16384x1024
    bf16_t* Vt   = Km + 16777216;              // 8 x 1024x2048
    bf16_t* U    = Vt + 16777216;              // 8 x 2048x2048
    bf16_t* xb   = U;                          // alias: dead before U written
    bf16_t* Wb   = U + 33554432;               // 3 x 1024x1024
    float*  l    = (float*)(Wb + 3145728);     // 16384

    k_cvt<<<dim3(2048), 256, 0, stream>>>(x, xb, 16777216 / 4, l);
    k_cvt3<<<dim3(1024, 1, 3), 256, 0, stream>>>(Wq, Wk, Wv, Wb);
    k_qkv3<<<dim3(8, 96), 512, 0, stream>>>(xb, Wb, Q, Vt, bq, bk, bv);
    k_scores<<<dim3(8, 64), 512, 0, stream>>>(Q, Km, U, l);
    k_pv<<<dim3(8, 32), 512, 0, stream>>>(U, Vt, (float*)d_out, l);
}

// Round 4
// 364.032 us; speedup vs baseline: 1.2101x; 1.0540x over previous
//
#include <hip/hip_runtime.h>
#include <stdint.h>

// Self-attention, B=8, S=2048, D=1024, fp32 in/out, bf16 MFMA compute.
//
// Pipeline:
//   1. k_cvt: x -> xb (bf16), zero l;  k_cvt3: Wq/Wk/Wv -> Wb
//   2. k_qkv3 (z=0,1): Q/K = xb @ W^T + b   (z=2): Vt = (xb @ Wv^T + bv)^T
//   3. k_scores: U = exp((Q @ K^T)/32) bf16 + atomic per-row sums into l
//   4. k_pv   : out = (U @ Vt^T) * (1/l[row])  (fp32 out)
//
// R9: bank-conflict swizzle fix on the R8 256x256/BK=32/ring-4 core.
//  R8 measured SQ_LDS_BANK_CONFLICT = 9.96M on k_qkv3 (~4 extra cyc per
//  ds_read_b128) -- a 4-way conflict per 16-lane quarter: with 64 B rows the
//  start-bank class is (row&1)*4 + slot (8 classes), and the R8 XOR key
//  (lr&3) wasted its low bit on row parity -> only 4 classes covered.
//  Fix: XOR key = (lr>>1)&3 (the row bits NOT already in the bank address):
//    read slot  = quad ^ ((lr>>1)&3)
//    stage slot = (t&3) ^ ((rowS>>1)&3)   (same involution, both sides)
//  -> 8 classes x 2 lanes = 2-way aliasing only (free, m136).
//  Everything else identical to R8 (race-free counted-vmcnt ring schedule,
//  proven by refcheck).
//
// ws layout:
//   [0,       33.5M)  Q        16384x1024 bf16
//   [33.5M,   67.1M)  K        16384x1024 bf16
//   [67.1M,  100.7M)  Vt       8 x 1024x2048 bf16
//   [100.7M, 167.8M)  U        8 x 2048x2048 bf16  (first half aliases xb)
//   [167.8M, 174.1M)  Wb       3 x 1024x1024 bf16
//   [174.1M, ...)     l        16384 fp32 (attn row sums, atomic)

typedef __bf16 bf16_t;
typedef __bf16 bf16x8 __attribute__((ext_vector_type(8)));
typedef __bf16 bf16x4 __attribute__((ext_vector_type(4)));
typedef float f32x4 __attribute__((ext_vector_type(4)));

__device__ __forceinline__ void gload_lds16(const bf16_t* g, bf16_t* l) {
    __builtin_amdgcn_global_load_lds((const __attribute__((address_space(1))) void*)g,
                                     (__attribute__((address_space(3))) void*)l,
                                     16, 0, 0);
}

// ---------------------------------------------------------------------------
// Core GEMM: C[M,N] = A[M,K] @ B[N,K]^T, bf16 row-major K-contiguous.
// Tile 256x256, BK=32, 512 threads (8 waves 2Mx4N), per-wave 8x4 16x16x32
// MFMA fragments (output 128x64 per wave).
// lds: caller-provided 65536 bf16 (128 KiB): 4 ring buffers of 16384 elems
// (A tile 8192 + B tile 8192). Epilogue (EPI 0/1) reuses it as 128x264 repack.
// EPI: 0 = (+bias[col]) -> bf16 coalesced stores
//      1 = exp(acc*scale) -> bf16 stores + atomic row sums into aux
//      2 = acc*(1/aux[row]) -> fp32 direct stores
//      3 = (+bias[col]) -> bf16 TRANSPOSED into Vt[b][col][row]
// ---------------------------------------------------------------------------
template <int EPI, int LDA, int LDB>
__device__ __forceinline__ void gemm256_core(
    bf16_t* __restrict__ lds,
    const bf16_t* __restrict__ A,
    const bf16_t* __restrict__ B,
    bf16_t* __restrict__ Cb, float* __restrict__ Cf, int ldc,
    float* __restrict__ aux, float scale, int K,
    int m0, int n0)
{
    const int t    = threadIdx.x;         // 0..511
    const int lane = t & 63;
    const int wave = t >> 6;              // 0..7
    const int wm   = wave >> 2;           // 0..1  (M half)
    const int wn   = wave & 3;            // 0..3  (N quarter)
    const int lr   = lane & 15;
    const int quad = lane >> 4;

    // Staging: thread t owns 16B slots {t, 512+t} of each tile half.
    // Physical slot s of row r holds logical chunk s ^ ((r>>1)&3) -- the
    // inverse of the read-side XOR (involution), so reads see linear data.
    const int rowS = t >> 2;                       // 0..127
    const int qS   = (t & 3) ^ ((rowS >> 1) & 3);
    const bf16_t* Ag = A + (size_t)(m0 + rowS) * LDA + qS * 8;
    const bf16_t* Bg = B + (size_t)(n0 + rowS) * LDB + qS * 8;
    const int dst0 = t * 8;                        // elems

    // Fragment read offsets (elems): row-major 256x32, slot XOR-swizzled by
    // (lr>>1)&3 -> per-16-lane-quarter start classes (row&1)*4 + slot cover
    // all 8 classes twice -> 2-way bank aliasing only (free).
    const int ko   = (quad ^ ((lr >> 1) & 3)) * 8;
    const int aoff = (wm * 128 + lr) * 32 + ko;
    const int boff = (wn * 64 + lr) * 32 + ko;

    f32x4 acc[8][4];
#pragma unroll
    for (int i = 0; i < 8; i++)
#pragma unroll
        for (int j = 0; j < 4; j++) acc[i][j] = (f32x4){0.f, 0.f, 0.f, 0.f};

    const int T = K >> 5;   // K32-steps (>= 3)

    // Prologue: stage tiles 0,1,2 (12 loads/thread), then require tile 0.
#pragma unroll
    for (int tt = 0; tt < 3; ++tt) {
        bf16_t* Ab = lds + tt * 16384;
        bf16_t* Bb = Ab + 8192;
        const int kt = tt * 32;
        gload_lds16(Ag + kt,                     Ab + dst0);
        gload_lds16(Ag + kt + (size_t)128 * LDA, Ab + 4096 + dst0);
        gload_lds16(Bg + kt,                     Bb + dst0);
        gload_lds16(Bg + kt + (size_t)128 * LDB, Bb + 4096 + dst0);
    }
    asm volatile("s_waitcnt vmcnt(8)" ::: "memory");
    __builtin_amdgcn_s_barrier();
    __builtin_amdgcn_sched_barrier(0);

    for (int tk = 0; tk < T; ++tk) {
        const bf16_t* Ab = lds + (tk & 3) * 16384;
        const bf16_t* Bb = Ab + 8192;
        bf16x8 af[8], bfr[4];
        // ---- phase 1: read A lo-half frags + all B frags, compute i=0..3
#pragma unroll
        for (int i = 0; i < 4; ++i)
            af[i] = *(const bf16x8*)(Ab + aoff + 512 * i);
#pragma unroll
        for (int j = 0; j < 4; ++j)
            bfr[j] = *(const bf16x8*)(Bb + boff + 512 * j);
        __builtin_amdgcn_s_barrier();              // B_{t,1}
        __builtin_amdgcn_sched_barrier(0);
        __builtin_amdgcn_s_setprio(1);
#pragma unroll
        for (int i = 0; i < 4; ++i)
#pragma unroll
            for (int j = 0; j < 4; ++j)
                acc[i][j] = __builtin_amdgcn_mfma_f32_16x16x32_bf16(af[i], bfr[j], acc[i][j], 0, 0, 0);
        __builtin_amdgcn_s_setprio(0);
        // ---- phase 2: read A hi-half frags, stage tile t+3, compute i=4..7
#pragma unroll
        for (int i = 4; i < 8; ++i)
            af[i] = *(const bf16x8*)(Ab + aoff + 512 * i);
        if (tk + 3 < T) {
            bf16_t* An = lds + ((tk + 3) & 3) * 16384;   // = buf of tile t-1 (dead)
            bf16_t* Bn = An + 8192;
            const int kt = (tk + 3) * 32;
            gload_lds16(Ag + kt,                     An + dst0);
            gload_lds16(Ag + kt + (size_t)128 * LDA, An + 4096 + dst0);
            gload_lds16(Bg + kt,                     Bn + dst0);
            gload_lds16(Bg + kt + (size_t)128 * LDB, Bn + 4096 + dst0);
            asm volatile("s_waitcnt vmcnt(8)" ::: "memory");   // tiles t+2,t+3 in flight
        } else if (tk + 2 < T) {
            asm volatile("s_waitcnt vmcnt(4)" ::: "memory");
        } else {
            asm volatile("s_waitcnt vmcnt(0)" ::: "memory");
        }
        __builtin_amdgcn_s_barrier();              // B_{t,2}: tile t+1 now visible to all
        __builtin_amdgcn_sched_barrier(0);
        __builtin_amdgcn_s_setprio(1);
#pragma unroll
        for (int i = 4; i < 8; ++i)
#pragma unroll
            for (int j = 0; j < 4; ++j)
                acc[i][j] = __builtin_amdgcn_mfma_f32_16x16x32_bf16(af[i], bfr[j], acc[i][j], 0, 0, 0);
        __builtin_amdgcn_s_setprio(0);
    }

    // Epilogue. C/D frag layout: col = lane&15, row = quad*4 + reg.
    if (EPI == 0 || EPI == 1) {
        // Repack half-by-half (wm half h -> 128x256) in LDS (stride 264),
        // then coalesced 16B stores; EPI1 also accumulates row sums.
#pragma unroll
        for (int h = 0; h < 2; ++h) {
            __syncthreads();
            if (wm == h) {
#pragma unroll
                for (int j = 0; j < 4; ++j) {
                    const int col = wn * 64 + j * 16 + lr;
                    const float bv = (EPI == 0) ? aux[n0 + col] : 0.f;
#pragma unroll
                    for (int i = 0; i < 8; ++i) {
                        const int row = i * 16 + quad * 4;
#pragma unroll
                        for (int r = 0; r < 4; ++r) {
                            float v = (EPI == 0) ? (acc[i][j][r] + bv)
                                                 : __expf(acc[i][j][r] * scale);
                            lds[(row + r) * 264 + col] = (__bf16)v;
                        }
                    }
                }
            }
            __syncthreads();
            const int r2 = t >> 2;            // 0..127
            const int c0 = (t & 3) * 8;       // interleaved col chunks
            float part = 0.f;
#pragma unroll
            for (int c = 0; c < 8; ++c) {
                bf16x8 v = *(const bf16x8*)(lds + r2 * 264 + c0 + c * 32);
                *(bf16x8*)(Cb + (size_t)(m0 + h * 128 + r2) * ldc + n0 + c0 + c * 32) = v;
                if (EPI == 1) {
#pragma unroll
                    for (int e = 0; e < 8; ++e) part += (float)v[e];
                }
            }
            if (EPI == 1) {
                part += __shfl_xor(part, 1);
                part += __shfl_xor(part, 2);
                if ((t & 3) == 0) atomicAdd(aux + m0 + h * 128 + r2, part);
            }
        }
    } else if (EPI == 2) {
#pragma unroll
        for (int i = 0; i < 8; ++i) {
            const int rowb = m0 + wm * 128 + i * 16 + quad * 4;
#pragma unroll
            for (int r = 0; r < 4; ++r) {
                const float s = 1.0f / aux[rowb + r];
                float* crow = Cf + (size_t)(rowb + r) * ldc + n0 + wn * 64 + lr;
#pragma unroll
                for (int j = 0; j < 4; ++j)
                    crow[j * 16] = acc[i][j][r] * s;
            }
        }
    } else {
        // EPI 3: transposed write into Vt[b][col][row], rows global = b*2048+s
#pragma unroll
        for (int j = 0; j < 4; ++j) {
            const int col = n0 + wn * 64 + j * 16 + lr;      // d index
            const float bv = aux[col];
#pragma unroll
            for (int i = 0; i < 8; ++i) {
                const int rowg = m0 + wm * 128 + i * 16 + quad * 4;  // global s
                const int b    = rowg >> 11;
                const int s    = rowg & 2047;
                bf16x4 p = { (__bf16)(acc[i][j][0] + bv), (__bf16)(acc[i][j][1] + bv),
                             (__bf16)(acc[i][j][2] + bv), (__bf16)(acc[i][j][3] + bv) };
                *(bf16x4*)(Cb + ((size_t)b << 21) + ((size_t)col << 11) + s) = p;
            }
        }
    }
}

// --------------------------- kernel wrappers -------------------------------

// Q/K/Vt projection, grid (8,96) = 768 blocks. xcd = lid&7; within an XCD,
// x' (weight n-tile, 4) fast, y' (A-strip, 8) middle, z' (matrix) slowest
// -> W_z (2 MB) L2-pinned per phase.
__global__ __launch_bounds__(512, 1) void k_qkv3(
    const bf16_t* __restrict__ xb, const bf16_t* __restrict__ Wb,
    bf16_t* __restrict__ Q, bf16_t* __restrict__ Vt,
    const float* __restrict__ bq, const float* __restrict__ bk,
    const float* __restrict__ bv)
{
    __shared__ bf16_t lds[65536];
    const int lid  = blockIdx.x + 8 * blockIdx.y;
    const int xcd  = lid & 7;
    const int slot = lid >> 3;          // 0..95
    const int z    = slot >> 5;         // 0..2, slowest
    const int rem  = slot & 31;
    const int xt   = rem & 3;           // fast (4 n-tiles)
    const int yt   = xcd * 8 + (rem >> 2);
    if (z < 2) {
        float* bias = (float*)((z == 0) ? bq : bk);
        gemm256_core<0, 1024, 1024>(lds, xb, Wb + (size_t)z * 1048576,
                                    Q + (size_t)z * 16777216, nullptr, 1024,
                                    bias, 0.f, 1024, yt * 256, xt * 256);
    } else {
        gemm256_core<3, 1024, 1024>(lds, xb, Wb + (size_t)2 * 1048576,
                                    Vt, nullptr, 0,
                                    (float*)bv, 0.f, 1024, yt * 256, xt * 256);
    }
}

// scores, grid (8,64) = 512 blocks: batch = lid&7 == XCD -> per-XCD working
// set is one batch's K matrix (4 MB = L2). x-tile fast.
__global__ __launch_bounds__(512, 1) void k_scores(
    const bf16_t* __restrict__ Q, const bf16_t* __restrict__ Km,
    bf16_t* __restrict__ U, float* __restrict__ l)
{
    __shared__ bf16_t lds[65536];
    const int lid = blockIdx.x + 8 * blockIdx.y;
    const int b   = lid & 7;
    const int si  = lid >> 3;           // 0..63
    const int xt  = si & 7;
    const int yt  = si >> 3;
    gemm256_core<1, 1024, 1024>(lds, Q + (size_t)b * 2048 * 1024,
                                Km + (size_t)b * 2048 * 1024,
                                U + (size_t)b * 2048 * 2048, nullptr, 2048,
                                l + b * 2048, 0.03125f, 1024,
                                yt * 256, xt * 256);
}

// PV, grid (8,32) = 256 blocks: batch = lid&7 == XCD -> per-XCD working set
// is one batch's Vt (4 MB = L2).
__global__ __launch_bounds__(512, 1) void k_pv(
    const bf16_t* __restrict__ U, const bf16_t* __restrict__ Vt,
    float* __restrict__ Out, float* __restrict__ l)
{
    __shared__ bf16_t lds[65536];
    const int lid = blockIdx.x + 8 * blockIdx.y;
    const int b   = lid & 7;
    const int si  = lid >> 3;           // 0..31
    const int xt  = si & 3;
    const int yt  = si >> 2;
    gemm256_core<2, 2048, 2048>(lds, U + (size_t)b * 2048 * 2048,
                                Vt + (size_t)b * 1024 * 2048,
                                nullptr, Out + (size_t)b * 2048 * 1024, 1024,
                                l + b * 2048, 0.f, 2048,
                                yt * 256, xt * 256);
}

// fp32 -> bf16 conversion, 4 elems/thread; also zeroes l (16384 floats)
__global__ __launch_bounds__(256) void k_cvt(
    const float* __restrict__ in, bf16_t* __restrict__ out, long ngroups,
    float* __restrict__ l)
{
    long idx    = (long)blockIdx.x * blockDim.x + threadIdx.x;
    long stride = (long)gridDim.x * blockDim.x;
    if (blockIdx.x < 64) l[blockIdx.x * 256 + threadIdx.x] = 0.f;
    for (long i = idx; i < ngroups; i += stride) {
        float4 v = ((const float4*)in)[i];
        bf16x4 o = { (__bf16)v.x, (__bf16)v.y, (__bf16)v.z, (__bf16)v.w };
        ((bf16x4*)out)[i] = o;
    }
}

// fused 3-weight fp32 -> bf16 (z selects source)
__global__ __launch_bounds__(256) void k_cvt3(
    const float* __restrict__ w0, const float* __restrict__ w1,
    const float* __restrict__ w2, bf16_t* __restrict__ out)
{
    const int z = blockIdx.z;
    const float* in = (z == 0) ? w0 : (z == 1) ? w1 : w2;
    bf16_t* o = out + (size_t)z * 1048576;
    long i = (long)blockIdx.x * blockDim.x + threadIdx.x;
    float4 v = ((const float4*)in)[i];
    bf16x4 ov = { (__bf16)v.x, (__bf16)v.y, (__bf16)v.z, (__bf16)v.w };
    ((bf16x4*)o)[i] = ov;
}

// ---------------------------------------------------------------------------

extern "C" void kernel_launch(void* const* d_in, const int* in_sizes, int n_in,
                              void* d_out, int out_size, void* d_ws, size_t ws_size,
                              hipStream_t stream)
{
    const float* x  = (const float*)d_in[0];
    const float* Wq = (const float*)d_in[1];
    const float* bq = (const float*)d_in[2];
    const float* Wk = (const float*)d_in[3];
    const float* bk = (const float*)d_in[4];
    const float* Wv = (const float*)d_in[5];
    const float* bv = (const float*)d_in[6];

    bf16_t* Q    = (bf16_t*)d_ws;              // 16384x1024
    bf16_t* Km   = Q + 16777216;               // 16384x1024
    bf16_t* Vt   = Km + 16777216;              // 8 x 1024x2048
    bf16_t* U    = Vt + 16777216;              // 8 x 2048x2048
    bf16_t* xb   = U;                          // alias: dead before U written
    bf16_t* Wb   = U + 33554432;               // 3 x 1024x1024
    float*  l    = (float*)(Wb + 3145728);     // 16384

    k_cvt<<<dim3(2048), 256, 0, stream>>>(x, xb, 16777216 / 4, l);
    k_cvt3<<<dim3(1024, 1, 3), 256, 0, stream>>>(Wq, Wk, Wv, Wb);
    k_qkv3<<<dim3(8, 96), 512, 0, stream>>>(xb, Wb, Q, Vt, bq, bk, bv);
    k_scores<<<dim3(8, 64), 512, 0, stream>>>(Q, Km, U, l);
    k_pv<<<dim3(8, 32), 512, 0, stream>>>(U, Vt, (float*)d_out, l);
}